// Round 2
// baseline (1516.605 us; speedup 1.0000x reference)
//
#include <hip/hip_runtime.h>
#include <hip/hip_bf16.h>

#define N_B 256
#define T_SEQ 32
#define DD 1024
#define HH 1024
#define KTOT 3072   // D + H + H

typedef short short8 __attribute__((ext_vector_type(8)));
typedef float floatx4 __attribute__((ext_vector_type(4)));
typedef unsigned short ushort_t;

// ---- scratch as device globals: no dependence on ws_size -------------------
__device__ __align__(16) ushort_t g_Wt[(size_t)4096 * KTOT];      // 24 MB bf16, [j][k]
__device__ __align__(16) ushort_t g_xb[(size_t)N_B * T_SEQ * DD]; // 16 MB bf16
__device__ __align__(16) ushort_t g_Hc[2][N_B * 2048];            // [h | attn] bf16
__device__ __align__(16) float    g_c[N_B * HH];                  // fp32 cell state

__device__ __forceinline__ float bf2f(ushort_t u){
    union { unsigned int i; float f; } v; v.i = ((unsigned int)u) << 16; return v.f;
}
__device__ __forceinline__ ushort_t f2bf(float f){
    union { unsigned int i; float f; } v; v.f = f;
    unsigned int i = v.i;
    unsigned int r = (i + 0x7FFFu + ((i >> 16) & 1u)) >> 16;
    return (ushort_t)r;
}

// ---------------------------------------------------------------------------
// Convert x (fp32) -> g_xb (bf16). 8 elements/thread. grid 4096 x 256.
// ---------------------------------------------------------------------------
__global__ __launch_bounds__(256) void cvt_x(const float* __restrict__ x)
{
    size_t i = ((size_t)blockIdx.x * 256 + threadIdx.x) * 8;
    float4 a = *(const float4*)(x + i);
    float4 b = *(const float4*)(x + i + 4);
    ushort_t r[8];
    r[0] = f2bf(a.x); r[1] = f2bf(a.y); r[2] = f2bf(a.z); r[3] = f2bf(a.w);
    r[4] = f2bf(b.x); r[5] = f2bf(b.y); r[6] = f2bf(b.z); r[7] = f2bf(b.w);
    *(uint4*)(g_xb + i) = *(const uint4*)r;
}

// ---------------------------------------------------------------------------
// Prepack: g_Wt[j][k] = {Wx,Wh,Wattn}[k][j] (fp32 -> bf16, transposed).
// grid (48, 64) x 256; 64(k) x 64(j) tile each.
// ---------------------------------------------------------------------------
__global__ __launch_bounds__(256) void prepack_w(
    const float* __restrict__ Wx, const float* __restrict__ Wh,
    const float* __restrict__ Wattn)
{
    __shared__ ushort_t tile[64][66];
    int k0 = blockIdx.x * 64, j0 = blockIdx.y * 64;
    const float* src; int krel;
    if (k0 < 1024)      { src = Wx;    krel = k0;        }
    else if (k0 < 2048) { src = Wh;    krel = k0 - 1024; }
    else                { src = Wattn; krel = k0 - 2048; }
    int c = threadIdx.x & 63, r4 = threadIdx.x >> 6;
    for (int rr = 0; rr < 64; rr += 4) {
        int r = rr + r4;
        tile[r][c] = f2bf(src[(size_t)(krel + r) * 4096 + j0 + c]);
    }
    __syncthreads();
    for (int rr = 0; rr < 64; rr += 4) {
        int j = rr + r4;
        g_Wt[(size_t)(j0 + j) * KTOT + k0 + c] = tile[c][j];
    }
}

// ---------------------------------------------------------------------------
// Init: h0 = c0 = mean over 16 spatial of A (fp32). grid 1024 x 256.
// ---------------------------------------------------------------------------
__global__ __launch_bounds__(256) void init_hc(const float* __restrict__ A)
{
    int gid = blockIdx.x * 256 + threadIdx.x;       // (n,h)
    int n = gid >> 10, h = gid & 1023;
    const float* ap = A + ((size_t)gid << 4);
    float4 a0 = *(const float4*)(ap);
    float4 a1 = *(const float4*)(ap + 4);
    float4 a2 = *(const float4*)(ap + 8);
    float4 a3 = *(const float4*)(ap + 12);
    float s = (a0.x+a0.y+a0.z+a0.w) + (a1.x+a1.y+a1.z+a1.w)
            + (a2.x+a2.y+a2.z+a2.w) + (a3.x+a3.y+a3.z+a3.w);
    s *= (1.0f / 16.0f);
    g_Hc[0][n * 2048 + h] = f2bf(s);
    g_c[gid] = s;
}

// ---------------------------------------------------------------------------
// Attention step: reads h-section of Hc[t&1], writes its attn-section.
// grid 256 (block per n) x 256 (4 h per thread).
// ---------------------------------------------------------------------------
__global__ __launch_bounds__(256) void attn_step(const float* __restrict__ A, int t)
{
    ushort_t* Hc = g_Hc[t & 1];
    int n = blockIdx.x, tid = threadIdx.x;
    const ushort_t* hp = Hc + n * 2048;
    const float* ap = A + ((size_t)n << 14);        // n*1024*16
    int hbase = tid * 4;

    float sp[16];
    #pragma unroll
    for (int l = 0; l < 16; ++l) sp[l] = 0.f;
    float av[4][16];
    #pragma unroll
    for (int i = 0; i < 4; ++i) {
        const float* ar = ap + ((size_t)(hbase + i) << 4);
        float4 b0 = *(const float4*)(ar);
        float4 b1 = *(const float4*)(ar + 4);
        float4 b2 = *(const float4*)(ar + 8);
        float4 b3 = *(const float4*)(ar + 12);
        av[i][0]=b0.x; av[i][1]=b0.y; av[i][2]=b0.z; av[i][3]=b0.w;
        av[i][4]=b1.x; av[i][5]=b1.y; av[i][6]=b1.z; av[i][7]=b1.w;
        av[i][8]=b2.x; av[i][9]=b2.y; av[i][10]=b2.z; av[i][11]=b2.w;
        av[i][12]=b3.x; av[i][13]=b3.y; av[i][14]=b3.z; av[i][15]=b3.w;
    }
    float hv[4];
    #pragma unroll
    for (int i = 0; i < 4; ++i) hv[i] = bf2f(hp[hbase + i]);
    #pragma unroll
    for (int i = 0; i < 4; ++i)
        #pragma unroll
        for (int l = 0; l < 16; ++l) sp[l] += hv[i] * av[i][l];

    #pragma unroll
    for (int l = 0; l < 16; ++l) {
        float v = sp[l];
        v += __shfl_xor(v, 32); v += __shfl_xor(v, 16); v += __shfl_xor(v, 8);
        v += __shfl_xor(v, 4);  v += __shfl_xor(v, 2);  v += __shfl_xor(v, 1);
        sp[l] = v;
    }
    __shared__ float red[4][16];
    int wv = tid >> 6, lane = tid & 63;
    if (lane == 0) {
        #pragma unroll
        for (int l = 0; l < 16; ++l) red[wv][l] = sp[l];
    }
    __syncthreads();
    float w[16], mx = -1e30f;
    #pragma unroll
    for (int l = 0; l < 16; ++l) {
        float s = (red[0][l] + red[1][l] + red[2][l] + red[3][l]) * 0.03125f;
        w[l] = s; mx = fmaxf(mx, s);
    }
    float sum = 0.f;
    #pragma unroll
    for (int l = 0; l < 16; ++l) { w[l] = __expf(w[l] - mx); sum += w[l]; }
    float inv = 1.f / sum;
    #pragma unroll
    for (int i = 0; i < 4; ++i) {
        float acc = 0.f;
        #pragma unroll
        for (int l = 0; l < 16; ++l) acc += av[i][l] * (w[l] * inv);
        Hc[n * 2048 + 1024 + hbase + i] = f2bf(acc);
    }
}

// ---------------------------------------------------------------------------
// Fused GEMM (256x4096, K=3072 = [x_t | h | attn] @ [Wx;Wh;Wattn]) + LSTM.
// 64x64 tiles, 256 blocks (XCD-swizzled), 4 waves (32x32 per wave).
// Gate-grouped B columns: block's j-rows = { g*1024 + hh0 + 0..15, g=0..3 }.
// ---------------------------------------------------------------------------
__global__ __launch_bounds__(256) void gemm_lstm(
    const float* __restrict__ bias, float* __restrict__ out, int t)
{
    __shared__ __align__(16) ushort_t lA[64 * 64];
    __shared__ __align__(16) ushort_t lB[64 * 64];
    __shared__ float lP[64 * 65];

    const ushort_t* Hin  = g_Hc[t & 1];
    ushort_t*       Hout = g_Hc[(t + 1) & 1];

    int b = blockIdx.x;
    int xcd = b & 7, r = b >> 3;
    int mt_ = r & 3, jt = xcd * 8 + (r >> 2);
    int n0 = mt_ * 64, hh0 = jt * 16;
    int tid = threadIdx.x;

    int m1 = tid >> 3, k8 = tid & 7;
    int m2 = m1 + 32;
    int koff = k8 * 8;

    const ushort_t* xr1 = g_xb + ((size_t)((n0 + m1) * T_SEQ + t)) * DD;
    const ushort_t* xr2 = g_xb + ((size_t)((n0 + m2) * T_SEQ + t)) * DD;
    const ushort_t* hr1 = Hin + (n0 + m1) * 2048 - 1024; // +k lands in [h|attn]
    const ushort_t* hr2 = Hin + (n0 + m2) * 2048 - 1024;
    int j1 = ((m1 >> 4) << 10) + hh0 + (m1 & 15);
    int j2 = ((m2 >> 4) << 10) + hh0 + (m2 & 15);
    const ushort_t* wr1 = g_Wt + (size_t)j1 * KTOT;
    const ushort_t* wr2 = g_Wt + (size_t)j2 * KTOT;

    int dA1 = m1 * 8 + (k8 ^ (m1 & 7));   // XOR-swizzled 16B-segment index
    int dA2 = m2 * 8 + (k8 ^ (m2 & 7));

    uint4* lA4 = (uint4*)lA; uint4* lB4 = (uint4*)lB;
    const short8* lA8 = (const short8*)lA;
    const short8* lB8 = (const short8*)lB;

    uint4 ra1 = *(const uint4*)(xr1 + koff);
    uint4 ra2 = *(const uint4*)(xr2 + koff);
    uint4 rb1 = *(const uint4*)(wr1 + koff);
    uint4 rb2 = *(const uint4*)(wr2 + koff);

    floatx4 acc[2][2] = {};

    int lane = tid & 63, wv = tid >> 6;
    int wm = wv >> 1, wn = wv & 1;
    int lm = lane & 15, lk = lane >> 4;
    int am0 = wm * 32 + lm, am1 = wm * 32 + 16 + lm;
    int bc0 = wn * 32 + lm, bc1 = wn * 32 + 16 + lm;

    for (int kt = 0; kt < 48; ++kt) {
        __syncthreads();
        lA4[dA1] = ra1; lA4[dA2] = ra2;
        lB4[dA1] = rb1; lB4[dA2] = rb2;
        __syncthreads();
        int k0n = (kt < 47) ? (kt + 1) * 64 : 0;   // kt=47: dummy (valid addr)
        ra1 = *(const uint4*)(((k0n < 1024) ? xr1 : hr1) + k0n + koff);
        ra2 = *(const uint4*)(((k0n < 1024) ? xr2 : hr2) + k0n + koff);
        rb1 = *(const uint4*)(wr1 + k0n + koff);
        rb2 = *(const uint4*)(wr2 + k0n + koff);
        #pragma unroll
        for (int ks = 0; ks < 2; ++ks) {
            int kq = ks * 4 + lk;
            short8 af0 = lA8[am0 * 8 + (kq ^ (am0 & 7))];
            short8 af1 = lA8[am1 * 8 + (kq ^ (am1 & 7))];
            short8 bf0 = lB8[bc0 * 8 + (kq ^ (bc0 & 7))];
            short8 bf1 = lB8[bc1 * 8 + (kq ^ (bc1 & 7))];
            acc[0][0] = __builtin_amdgcn_mfma_f32_16x16x32_bf16(af0, bf0, acc[0][0], 0, 0, 0);
            acc[0][1] = __builtin_amdgcn_mfma_f32_16x16x32_bf16(af0, bf1, acc[0][1], 0, 0, 0);
            acc[1][0] = __builtin_amdgcn_mfma_f32_16x16x32_bf16(af1, bf0, acc[1][0], 0, 0, 0);
            acc[1][1] = __builtin_amdgcn_mfma_f32_16x16x32_bf16(af1, bf1, acc[1][1], 0, 0, 0);
        }
    }

    // stage preact tile to LDS so each thread gathers its 4 gates
    #pragma unroll
    for (int mt = 0; mt < 2; ++mt)
        #pragma unroll
        for (int nt = 0; nt < 2; ++nt)
            #pragma unroll
            for (int q = 0; q < 4; ++q) {
                int mrow = wm * 32 + mt * 16 + lk * 4 + q;
                int ccol = wn * 32 + nt * 16 + lm;
                lP[mrow * 65 + ccol] = acc[mt][nt][q];
            }
    __syncthreads();

    #pragma unroll
    for (int q = 0; q < 4; ++q) {
        int idx = tid + q * 256;
        int nl = idx >> 4, hl = idx & 15;
        float ai  = lP[nl * 65 +      hl] + bias[       hh0 + hl];
        float afv = lP[nl * 65 + 16 + hl] + bias[1024 + hh0 + hl];
        float ao  = lP[nl * 65 + 32 + hl] + bias[2048 + hh0 + hl];
        float ag  = lP[nl * 65 + 48 + hl] + bias[3072 + hh0 + hl];
        float iv = 1.f / (1.f + __expf(-ai));
        float fv = 1.f / (1.f + __expf(-afv));
        float ov = 1.f / (1.f + __expf(-ao));
        float gv = tanhf(ag);
        int ng = n0 + nl, hg = hh0 + hl;
        float cold = g_c[ng * 1024 + hg];
        float cnew = fv * cold + iv * gv;
        float hnew = ov * tanhf(cnew);
        g_c[ng * 1024 + hg] = cnew;
        Hout[ng * 2048 + hg] = f2bf(hnew);
        out[(size_t)ng * (T_SEQ * HH) + (size_t)t * HH + hg] = hnew;
    }
}

// ---------------------------------------------------------------------------
extern "C" void kernel_launch(void* const* d_in, const int* in_sizes, int n_in,
                              void* d_out, int out_size, void* d_ws, size_t ws_size,
                              hipStream_t stream) {
    const float* x     = (const float*)d_in[0];
    const float* A     = (const float*)d_in[1];
    const float* Wx    = (const float*)d_in[2];
    const float* Wh    = (const float*)d_in[3];
    const float* Wattn = (const float*)d_in[4];
    const float* bias  = (const float*)d_in[5];
    float* out = (float*)d_out;

    cvt_x<<<4096, 256, 0, stream>>>(x);
    prepack_w<<<dim3(48, 64), 256, 0, stream>>>(Wx, Wh, Wattn);
    init_hc<<<1024, 256, 0, stream>>>(A);
    for (int t = 0; t < T_SEQ; ++t) {
        attn_step<<<256, 256, 0, stream>>>(A, t);
        gemm_lstm<<<256, 256, 0, stream>>>(bias, out, t);
    }
}